// Round 6
// baseline (119.496 us; speedup 1.0000x reference)
//
#include <hip/hip_runtime.h>

#define E_DIM 256
#define S_DIM 2048
#define B_DIM 8

typedef unsigned short u16;
typedef __bf16 bf16x8 __attribute__((ext_vector_type(8)));
typedef float f32x4 __attribute__((ext_vector_type(4)));
typedef u16 u16x8 __attribute__((ext_vector_type(8)));
typedef u16 u16x4 __attribute__((ext_vector_type(4)));

__device__ inline u16 f2bf(float f) {
  unsigned u = __builtin_bit_cast(unsigned, f);
  return (u16)((u + 0x7FFF + ((u >> 16) & 1)) >> 16);  // RTNE, finite inputs
}
__device__ inline float bf2f(u16 v) {
  unsigned u = ((unsigned)v) << 16;
  return __builtin_bit_cast(float, u);
}

// ---------------------------------------------------------------------------
// Prep: Wq, Wo (fp32 [f][e]) -> bf16 [f][e]
// ---------------------------------------------------------------------------
__global__ __launch_bounds__(256) void convert_w(
    const float* __restrict__ Wq, const float* __restrict__ Wo,
    u16* __restrict__ Wqb, u16* __restrict__ Wob) {
  int idx = (blockIdx.x * 256 + threadIdx.x) * 4;  // grid 128 -> 131072 elems
  const float* src;
  u16* dst;
  if (idx < 65536) { src = Wq + idx; dst = Wqb + idx; }
  else { src = Wo + (idx - 65536); dst = Wob + (idx - 65536); }
  float4 v = *(const float4*)src;
  ushort4 o = make_ushort4(f2bf(v.x), f2bf(v.y), f2bf(v.z), f2bf(v.w));
  *(ushort4*)dst = o;
}

// ---------------------------------------------------------------------------
// Fused: one block = (b, 64-s tile), 1024 threads (16 waves), grid 256 = 1/CU.
//  P0: stage xt[r][e] bf16, r=0..79 (t = s0-4+r; r>=72 or OOB -> 0)
//  P1: q = xt.Wq^T + bq (MFMA, M=80 N=256 K=256) -> qt bf16 rows 0..71
//      waves 4m x 4n; m-frag 4 rides on mi==0 waves
//  P2: banded energies; per-wave: 4 s-rows x all 256 f, si-pairs in lane
//      halves, 5-round shfl_xor butterfly, softmax in-registers -> ldsw
//  P3: pooled[s][e] = sum_l w[s][l]*xt[s+l][e] (bf16, aliases qt)
//  P4: out[b][f][s] = (pooled.Wo^T + bo)/9 (MFMA, M=64 N=256 K=256)
// Zero-staged OOB rows give q_row = bq and zero-padded pooling exactly.
// ---------------------------------------------------------------------------
#define TS 64
#define QR 72      // valid q rows: t = s0-4 .. s0+67
#define XROWS 80   // padded to 5 m-frags
#define XSTR 264   // u16 row stride (132 dw ≡ 4 mod 32: b128 conflict-free)
#define QSTR 266   // u16 (133 dw odd)
#define PSTR 264

__global__ __launch_bounds__(1024) void fused_attn(
    const float* __restrict__ x, const u16* __restrict__ Wqb,
    const float* __restrict__ bq, const u16* __restrict__ Wob,
    const float* __restrict__ bo, float* __restrict__ out) {
  // LDS: xt 42240 | qt 38304 (pooled 33792 aliases) | ldsw 2304  = 82848 B
  __shared__ __align__(16) char smem[82848];
  u16* xt = (u16*)smem;
  u16* qt = (u16*)(smem + 42240);
  u16* pooled = qt;
  float* ldsw = (float*)(smem + 80544);  // [64][9]

  const int tid = threadIdx.x;
  const int s0 = blockIdx.x * TS;
  const int b = blockIdx.y;
  const int wave = tid >> 6, lane = tid & 63;
  const int lm = lane & 15, lk = lane >> 4;
  const int mi = wave & 3, nj = wave >> 2;

  // ---- P0 pass A: rows 0..63 (lane = row, wave = 16-e slice) ----
  {
    const int r = lane;
    const int t = s0 - 4 + r;
    const bool v = (t >= 0) && (t < S_DIM);
    const float* __restrict__ xb = x + (size_t)b * E_DIM * S_DIM + t;
    float tmp[16];
#pragma unroll
    for (int c = 0; c < 16; ++c)
      tmp[c] = v ? xb[(size_t)(wave * 16 + c) * S_DIM] : 0.f;
    u16x8 w0, w1;
#pragma unroll
    for (int u = 0; u < 8; ++u) { w0[u] = f2bf(tmp[u]); w1[u] = f2bf(tmp[8 + u]); }
    *(u16x8*)&xt[r * XSTR + wave * 16] = w0;
    *(u16x8*)&xt[r * XSTR + wave * 16 + 8] = w1;
  }
  // ---- P0 pass B: rows 64..79 (first 4 waves) ----
  if (tid < 256) {
    const int r = 64 + (lane & 15);
    const int t = s0 - 4 + r;
    const bool v = (r < QR) && (t < S_DIM);  // t >= 60 always
    const int eb = wave * 64 + (lane >> 4) * 16;
    const float* __restrict__ xb = x + (size_t)b * E_DIM * S_DIM + t;
    float tmp[16];
#pragma unroll
    for (int c = 0; c < 16; ++c)
      tmp[c] = v ? xb[(size_t)(eb + c) * S_DIM] : 0.f;
    u16x8 w0, w1;
#pragma unroll
    for (int u = 0; u < 8; ++u) { w0[u] = f2bf(tmp[u]); w1[u] = f2bf(tmp[8 + u]); }
    *(u16x8*)&xt[r * XSTR + eb] = w0;
    *(u16x8*)&xt[r * XSTR + eb + 8] = w1;
  }
  __syncthreads();

  // ---- P1: K1 MFMA -> qt rows 0..71 ----
  {
    const f32x4 zero = {0.f, 0.f, 0.f, 0.f};
    f32x4 acc0[4], acc1[4];
#pragma unroll
    for (int j = 0; j < 4; ++j) { acc0[j] = zero; acc1[j] = zero; }
#pragma unroll
    for (int k0 = 0; k0 < 8; ++k0) {
      bf16x8 af0 = *(const bf16x8*)&xt[(mi * 16 + lm) * XSTR + k0 * 32 + lk * 8];
      bf16x8 af1;
      if (mi == 0) af1 = *(const bf16x8*)&xt[(64 + lm) * XSTR + k0 * 32 + lk * 8];
      bf16x8 bfr[4];
#pragma unroll
      for (int j = 0; j < 4; ++j)
        bfr[j] = *(const bf16x8*)&Wqb[(size_t)(nj * 64 + j * 16 + lm) * E_DIM +
                                      k0 * 32 + lk * 8];
#pragma unroll
      for (int j = 0; j < 4; ++j) {
        acc0[j] = __builtin_amdgcn_mfma_f32_16x16x32_bf16(af0, bfr[j], acc0[j], 0, 0, 0);
        if (mi == 0)
          acc1[j] = __builtin_amdgcn_mfma_f32_16x16x32_bf16(af1, bfr[j], acc1[j], 0, 0, 0);
      }
    }
#pragma unroll
    for (int j = 0; j < 4; ++j) {
      int f = nj * 64 + j * 16 + lm;
      float bv = bq[f];
#pragma unroll
      for (int r2 = 0; r2 < 4; ++r2) {
        int row = mi * 16 + lk * 4 + r2;
        qt[row * QSTR + f] = f2bf(acc0[j][r2] + bv);
      }
      if (mi == 0 && lk < 2) {  // rows 64..71 only
#pragma unroll
        for (int r2 = 0; r2 < 4; ++r2) {
          int row = 64 + lk * 4 + r2;
          qt[row * QSTR + f] = f2bf(acc1[j][r2] + bv);
        }
      }
    }
  }
  __syncthreads();

  // ---- P2: banded energies, in-wave reduce + softmax -> ldsw ----
  {
    const int half = lane >> 5;   // 0: si {0,1}, 1: si {2,3}
    const int fl = lane & 31;
    const int sbase = half * 2;
    float accE[2][9];
#pragma unroll
    for (int si = 0; si < 2; ++si)
#pragma unroll
      for (int l = 0; l < 9; ++l) accE[si][l] = 0.f;
#pragma unroll
    for (int fc = 0; fc < 2; ++fc) {
      int fbase = fl * 8 + fc * 4;
      float4 rr[10];
#pragma unroll
      for (int i = 0; i < 10; ++i) {
        u16x4 v = *(const u16x4*)&qt[(4 * wave + sbase + i) * QSTR + fbase];
        rr[i] = make_float4(bf2f(v[0]), bf2f(v[1]), bf2f(v[2]), bf2f(v[3]));
      }
#pragma unroll
      for (int si = 0; si < 2; ++si) {
        float4 c = rr[si + 4];
#pragma unroll
        for (int l = 0; l < 9; ++l) {
          float4 r = rr[si + l];
          accE[si][l] += c.x * r.x + c.y * r.y + c.z * r.z + c.w * r.w;
        }
      }
    }
#pragma unroll
    for (int off = 1; off < 32; off <<= 1)
#pragma unroll
      for (int si = 0; si < 2; ++si)
#pragma unroll
        for (int l = 0; l < 9; ++l) accE[si][l] += __shfl_xor(accE[si][l], off, 64);
    if (fl == 0) {
#pragma unroll
      for (int si = 0; si < 2; ++si) {
        int s = 4 * wave + sbase + si;
        float e[9];
#pragma unroll
        for (int l = 0; l < 9; ++l) e[l] = accE[si][l] * (1.0f / 24.0f);
        float m = e[0];
#pragma unroll
        for (int l = 1; l < 9; ++l) m = fmaxf(m, e[l]);
        float sum = 0.f;
#pragma unroll
        for (int l = 0; l < 9; ++l) { e[l] = __expf(e[l] - m); sum += e[l]; }
        float inv = 1.0f / sum;
#pragma unroll
        for (int l = 0; l < 9; ++l) ldsw[s * 9 + l] = e[l] * inv;
      }
    }
  }
  __syncthreads();

  // ---- P3: pooled[s][e] = sum_l w[s][l] * xt[s+l][e]  (overlays qt) ----
  {
    const int s = lane;        // 0..63
    const int ew = wave * 16;  // 16 e per thread
    float w9[9];
#pragma unroll
    for (int l = 0; l < 9; ++l) w9[l] = ldsw[s * 9 + l];
#pragma unroll
    for (int c = 0; c < 2; ++c) {
      int e8 = ew + c * 8;
      float o[8];
#pragma unroll
      for (int u = 0; u < 8; ++u) o[u] = 0.f;
#pragma unroll
      for (int l = 0; l < 9; ++l) {
        u16x8 xv = *(const u16x8*)&xt[(s + l) * XSTR + e8];
#pragma unroll
        for (int u = 0; u < 8; ++u) o[u] += w9[l] * bf2f(xv[u]);
      }
      u16x8 pv;
#pragma unroll
      for (int u = 0; u < 8; ++u) pv[u] = f2bf(o[u]);
      *(u16x8*)&pooled[s * PSTR + e8] = pv;
    }
  }
  __syncthreads();

  // ---- P4: K3 MFMA -> out[b][f][s] ----
  {
    const f32x4 zero = {0.f, 0.f, 0.f, 0.f};
    f32x4 acc[4];
#pragma unroll
    for (int j = 0; j < 4; ++j) acc[j] = zero;
#pragma unroll
    for (int k0 = 0; k0 < 8; ++k0) {
      bf16x8 af = *(const bf16x8*)&pooled[(mi * 16 + lm) * PSTR + k0 * 32 + lk * 8];
      bf16x8 bfr[4];
#pragma unroll
      for (int j = 0; j < 4; ++j)
        bfr[j] = *(const bf16x8*)&Wob[(size_t)(nj * 64 + j * 16 + lm) * E_DIM +
                                      k0 * 32 + lk * 8];
#pragma unroll
      for (int j = 0; j < 4; ++j)
        acc[j] = __builtin_amdgcn_mfma_f32_16x16x32_bf16(af, bfr[j], acc[j], 0, 0, 0);
    }
#pragma unroll
    for (int j = 0; j < 4; ++j) {
      int f = nj * 64 + j * 16 + lm;
      float bv = bo[f];
      int s = s0 + mi * 16 + lk * 4;
      float4 w = make_float4((acc[j][0] + bv) * (1.0f / 9.0f),
                             (acc[j][1] + bv) * (1.0f / 9.0f),
                             (acc[j][2] + bv) * (1.0f / 9.0f),
                             (acc[j][3] + bv) * (1.0f / 9.0f));
      *(float4*)&out[((size_t)b * E_DIM + f) * S_DIM + s] = w;
    }
  }
}

// ---------------------------------------------------------------------------
extern "C" void kernel_launch(void* const* d_in, const int* in_sizes, int n_in,
                              void* d_out, int out_size, void* d_ws, size_t ws_size,
                              hipStream_t stream) {
  const float* x = (const float*)d_in[0];
  const float* Wq = (const float*)d_in[1];
  const float* bq = (const float*)d_in[2];
  const float* Wo = (const float*)d_in[3];
  const float* bo = (const float*)d_in[4];
  float* out = (float*)d_out;

  u16* Wqb = (u16*)d_ws;
  u16* Wob = Wqb + 65536;

  convert_w<<<128, 256, 0, stream>>>(Wq, Wo, Wqb, Wob);
  fused_attn<<<dim3(S_DIM / TS, B_DIM), 1024, 0, stream>>>(x, Wqb, bq, Wob, bo, out);
}

// Round 7
// 105.339 us; speedup vs baseline: 1.1344x; 1.1344x over previous
//
#include <hip/hip_runtime.h>

#define E_DIM 256
#define S_DIM 2048
#define B_DIM 8

typedef unsigned short u16;
typedef __bf16 bf16x8 __attribute__((ext_vector_type(8)));
typedef float f32x4 __attribute__((ext_vector_type(4)));
typedef u16 u16x8 __attribute__((ext_vector_type(8)));
typedef u16 u16x4 __attribute__((ext_vector_type(4)));

__device__ inline u16 f2bf(float f) {
  unsigned u = __builtin_bit_cast(unsigned, f);
  return (u16)((u + 0x7FFF + ((u >> 16) & 1)) >> 16);  // RTNE, finite inputs
}
__device__ inline float bf2f(u16 v) {
  unsigned u = ((unsigned)v) << 16;
  return __builtin_bit_cast(float, u);
}

// ---------------------------------------------------------------------------
// Prep: Wq, Wo (fp32 [f][e]) -> bf16 [f][e]
// ---------------------------------------------------------------------------
__global__ __launch_bounds__(256) void convert_w(
    const float* __restrict__ Wq, const float* __restrict__ Wo,
    u16* __restrict__ Wqb, u16* __restrict__ Wob) {
  int idx = (blockIdx.x * 256 + threadIdx.x) * 4;  // grid 128 -> 131072 elems
  const float* src;
  u16* dst;
  if (idx < 65536) { src = Wq + idx; dst = Wqb + idx; }
  else { src = Wo + (idx - 65536); dst = Wob + (idx - 65536); }
  float4 v = *(const float4*)src;
  ushort4 o = make_ushort4(f2bf(v.x), f2bf(v.y), f2bf(v.z), f2bf(v.w));
  *(ushort4*)dst = o;
}

// ---------------------------------------------------------------------------
// Fused: one block = (b, 32-s tile), 512 threads (8 waves), grid 512 = 2/CU.
// 4 barriers. Weights consumed from prefetched VGPRs (issued across phases).
//  pre: prefetch all Wq frags (hide under P0's x loads)
//  P0: stage xt[r][e] bf16, r=0..47 (t = s0-4+r; r>=40 or OOB -> 0)
//  P1: q = xt.Wq^T + bq (MFMA, M=48 N=256 K=256) -> qt bf16 rows 0..39
//      then prefetch Wo j=0 frags (hide under P2/P3)
//  P2: banded energies fully in-wave: wave owns 4 s-rows x all 256 f,
//      si-pairs in lane halves, 5-round shfl_xor, softmax in-registers -> ldsw
//  P3: pooled[s][e] = sum_l w[s][l]*xt[s+l][e] (bf16, aliases qt)
//  P4: prefetch Wo j=1; out[b][f][s] = (pooled.Wo^T + bo)/9 (MFMA, M=32)
// Zero-staged OOB rows give q_row = bq and zero-padded pooling exactly.
// ---------------------------------------------------------------------------
#define TS 32
#define QR 40      // valid q rows: t = s0-4 .. s0+35
#define XROWS 48   // padded to 3 m-frags
#define XSTR 264   // u16 row stride (132 dw ≡ 4 mod 32: b128 conflict-free)
#define QSTR 266   // u16 (133 dw odd: banded reads conflict-free)
#define PSTR 264

__global__ __launch_bounds__(512, 4) void fused_attn(
    const float* __restrict__ x, const u16* __restrict__ Wqb,
    const float* __restrict__ bq, const u16* __restrict__ Wob,
    const float* __restrict__ bo, float* __restrict__ out) {
  // LDS: xt 25344 | qt 21280 (pooled 16896 aliases) | ldsw 1152 = 47776 B
  __shared__ __align__(16) char smem[47776];
  u16* xt = (u16*)smem;
  u16* qt = (u16*)(smem + 25344);
  u16* pooled = qt;
  float* ldsw = (float*)(smem + 46624);  // [32][9]

  const int tid = threadIdx.x;
  const int s0 = blockIdx.x * TS;
  const int b = blockIdx.y;
  const int wave = tid >> 6, lane = tid & 63;
  const int lm = lane & 15, lk = lane >> 4;

  // ---- prefetch all Wq fragments (f-slice = wave*32, j<2) ----
  bf16x8 wq[2][8];
  {
    const u16* __restrict__ p = Wqb + (size_t)(wave * 32 + lm) * E_DIM + lk * 8;
#pragma unroll
    for (int j = 0; j < 2; ++j)
#pragma unroll
      for (int k0 = 0; k0 < 8; ++k0)
        wq[j][k0] = *(const bf16x8*)&p[(size_t)j * 16 * E_DIM + k0 * 32];
  }

  // ---- P0: stage xt. lane = row (valid < 48), wave = 32-e slice ----
  {
    const int r = lane;
    const int t = s0 - 4 + r;
    const bool v = (r < QR) && (t >= 0) && (t < S_DIM);
    if (r < XROWS) {
      const float* __restrict__ xb = x + (size_t)b * E_DIM * S_DIM + t;
      const int ebase = wave * 32;
#pragma unroll
      for (int c = 0; c < 4; ++c) {
        u16x8 v8;
#pragma unroll
        for (int u = 0; u < 8; ++u) {
          float xv = v ? xb[(size_t)(ebase + c * 8 + u) * S_DIM] : 0.f;
          v8[u] = f2bf(xv);
        }
        *(u16x8*)&xt[r * XSTR + ebase + c * 8] = v8;
      }
    }
  }
  __syncthreads();

  // ---- P1: K1 MFMA -> qt rows 0..39 (M=48, wave f-slice wave*32) ----
  {
    const f32x4 zero = {0.f, 0.f, 0.f, 0.f};
    f32x4 acc[3][2];
#pragma unroll
    for (int i = 0; i < 3; ++i)
#pragma unroll
      for (int j = 0; j < 2; ++j) acc[i][j] = zero;
#pragma unroll
    for (int k0 = 0; k0 < 8; ++k0) {
      bf16x8 af[3];
#pragma unroll
      for (int i = 0; i < 3; ++i)
        af[i] = *(const bf16x8*)&xt[(i * 16 + lm) * XSTR + k0 * 32 + lk * 8];
#pragma unroll
      for (int i = 0; i < 3; ++i)
#pragma unroll
        for (int j = 0; j < 2; ++j)
          acc[i][j] = __builtin_amdgcn_mfma_f32_16x16x32_bf16(af[i], wq[j][k0], acc[i][j], 0, 0, 0);
    }
#pragma unroll
    for (int j = 0; j < 2; ++j) {
      int f = wave * 32 + j * 16 + lm;
      float bv = bq[f];
#pragma unroll
      for (int i = 0; i < 3; ++i) {
        int row = i * 16 + lk * 4;
#pragma unroll
        for (int r2 = 0; r2 < 4; ++r2)
          if (row + r2 < QR) qt[(row + r2) * QSTR + f] = f2bf(acc[i][j][r2] + bv);
      }
    }
  }
  // ---- prefetch Wo j=0 frags (lands during P2/P3) ----
  bf16x8 wo0[8];
  {
    const u16* __restrict__ p = Wob + (size_t)(wave * 32 + lm) * E_DIM + lk * 8;
#pragma unroll
    for (int k0 = 0; k0 < 8; ++k0) wo0[k0] = *(const bf16x8*)&p[k0 * 32];
  }
  __syncthreads();

  // ---- P2: banded energies in-wave + softmax -> ldsw ----
  {
    const int half = lane >> 5;  // 0: si {0,1}, 1: si {2,3}
    const int fl = lane & 31;
    const int sbase = half * 2;
    float accE[2][9];
#pragma unroll
    for (int si = 0; si < 2; ++si)
#pragma unroll
      for (int l = 0; l < 9; ++l) accE[si][l] = 0.f;
#pragma unroll
    for (int fc = 0; fc < 2; ++fc) {
      int fbase = fl * 8 + fc * 4;
      float4 rr[10];
#pragma unroll
      for (int i = 0; i < 10; ++i) {
        u16x4 v = *(const u16x4*)&qt[(4 * wave + sbase + i) * QSTR + fbase];
        rr[i] = make_float4(bf2f(v[0]), bf2f(v[1]), bf2f(v[2]), bf2f(v[3]));
      }
#pragma unroll
      for (int si = 0; si < 2; ++si) {
        float4 c = rr[si + 4];
#pragma unroll
        for (int l = 0; l < 9; ++l) {
          float4 r = rr[si + l];
          accE[si][l] += c.x * r.x + c.y * r.y + c.z * r.z + c.w * r.w;
        }
      }
    }
#pragma unroll
    for (int off = 1; off < 32; off <<= 1)
#pragma unroll
      for (int si = 0; si < 2; ++si)
#pragma unroll
        for (int l = 0; l < 9; ++l) accE[si][l] += __shfl_xor(accE[si][l], off, 64);
    if (fl == 0) {
#pragma unroll
      for (int si = 0; si < 2; ++si) {
        int s = 4 * wave + sbase + si;
        float e[9];
#pragma unroll
        for (int l = 0; l < 9; ++l) e[l] = accE[si][l] * (1.0f / 24.0f);
        float m = e[0];
#pragma unroll
        for (int l = 1; l < 9; ++l) m = fmaxf(m, e[l]);
        float sum = 0.f;
#pragma unroll
        for (int l = 0; l < 9; ++l) { e[l] = __expf(e[l] - m); sum += e[l]; }
        float inv = 1.0f / sum;
#pragma unroll
        for (int l = 0; l < 9; ++l) ldsw[s * 9 + l] = e[l] * inv;
      }
    }
  }
  __syncthreads();

  // ---- P3: pooled[s][e] = sum_l w[s][l] * xt[s+l][e]  (overlays qt) ----
  {
    const int s = tid & 31, ep = tid >> 5;  // ep 0..15, 16 e each
    float w9[9];
#pragma unroll
    for (int l = 0; l < 9; ++l) w9[l] = ldsw[s * 9 + l];
#pragma unroll
    for (int c = 0; c < 2; ++c) {
      int e8 = ep * 16 + c * 8;
      float o[8];
#pragma unroll
      for (int u = 0; u < 8; ++u) o[u] = 0.f;
#pragma unroll
      for (int l = 0; l < 9; ++l) {
        u16x8 xv = *(const u16x8*)&xt[(s + l) * XSTR + e8];
#pragma unroll
        for (int u = 0; u < 8; ++u) o[u] += w9[l] * bf2f(xv[u]);
      }
      u16x8 pv;
#pragma unroll
      for (int u = 0; u < 8; ++u) pv[u] = f2bf(o[u]);
      *(u16x8*)&pooled[s * PSTR + e8] = pv;
    }
  }
  __syncthreads();

  // ---- P4: K3 MFMA -> out[b][f][s] (M=32, wave f-slice wave*32) ----
  {
    bf16x8 wo1[8];
    const u16* __restrict__ p = Wob + (size_t)(wave * 32 + 16 + lm) * E_DIM + lk * 8;
#pragma unroll
    for (int k0 = 0; k0 < 8; ++k0) wo1[k0] = *(const bf16x8*)&p[k0 * 32];

    const f32x4 zero = {0.f, 0.f, 0.f, 0.f};
    f32x4 acc[2][2];
#pragma unroll
    for (int i = 0; i < 2; ++i)
#pragma unroll
      for (int j = 0; j < 2; ++j) acc[i][j] = zero;
#pragma unroll
    for (int k0 = 0; k0 < 8; ++k0) {
      bf16x8 af[2];
#pragma unroll
      for (int i = 0; i < 2; ++i)
        af[i] = *(const bf16x8*)&pooled[(i * 16 + lm) * PSTR + k0 * 32 + lk * 8];
#pragma unroll
      for (int i = 0; i < 2; ++i) {
        acc[i][0] = __builtin_amdgcn_mfma_f32_16x16x32_bf16(af[i], wo0[k0], acc[i][0], 0, 0, 0);
        acc[i][1] = __builtin_amdgcn_mfma_f32_16x16x32_bf16(af[i], wo1[k0], acc[i][1], 0, 0, 0);
      }
    }
#pragma unroll
    for (int j = 0; j < 2; ++j) {
      int f = wave * 32 + j * 16 + lm;
      float bv = bo[f];
#pragma unroll
      for (int i = 0; i < 2; ++i) {
        int s = s0 + i * 16 + lk * 4;
        float4 w = make_float4((acc[i][j][0] + bv) * (1.0f / 9.0f),
                               (acc[i][j][1] + bv) * (1.0f / 9.0f),
                               (acc[i][j][2] + bv) * (1.0f / 9.0f),
                               (acc[i][j][3] + bv) * (1.0f / 9.0f));
        *(float4*)&out[((size_t)b * E_DIM + f) * S_DIM + s] = w;
      }
    }
  }
}

// ---------------------------------------------------------------------------
extern "C" void kernel_launch(void* const* d_in, const int* in_sizes, int n_in,
                              void* d_out, int out_size, void* d_ws, size_t ws_size,
                              hipStream_t stream) {
  const float* x = (const float*)d_in[0];
  const float* Wq = (const float*)d_in[1];
  const float* bq = (const float*)d_in[2];
  const float* Wo = (const float*)d_in[3];
  const float* bo = (const float*)d_in[4];
  float* out = (float*)d_out;

  u16* Wqb = (u16*)d_ws;
  u16* Wob = Wqb + 65536;

  convert_w<<<128, 256, 0, stream>>>(Wq, Wo, Wqb, Wob);
  fused_attn<<<dim3(S_DIM / TS, B_DIM), 512, 0, stream>>>(x, Wqb, bq, Wob, bo, out);
}